// Round 2
// baseline (469.190 us; speedup 1.0000x reference)
//
#include <hip/hip_runtime.h>

typedef int   v4i   __attribute__((ext_vector_type(4)));
typedef unsigned long u64x2 __attribute__((ext_vector_type(2)));

#define HDIM 768
#define NTOK 32768

// ---- workspace layout (bytes) -- footprint unchanged vs previous version ----
static constexpr size_t WX_OFF   = 0;                   // int8 A8 [NTOK*HDIM]
static constexpr size_t WINT_OFF = 25165824;            // int8 W8 [HDIM*HDIM] = 589824 B used (slot is 1179648)
static constexpr size_t FACT_OFF = WINT_OFF + 589824;   // uint32[NTOK] per-row LN factor (131072 B, fits W slot spare)
static constexpr size_t RS1_OFF  = WINT_OFF + 1179648;  // double[768]
static constexpr size_t RS2_OFF  = RS1_OFF + 6144;      // double[768]
static constexpr size_t BS_OFF   = RS2_OFF + 6144;      // float [768] bias_scale
static constexpr size_t BINT_OFF = BS_OFF + 3072;       // int   [768] b_int
static constexpr size_t LNBI_OFF = BINT_OFF + 3072;     // int   [768] LN bias_int
static constexpr size_t SFO_OFF  = LNBI_OFF + 3072;     // float [768] sf_out
static constexpr size_t SC_OFF   = SFO_OFF + 3072;      // scalars: [0]min1 [1]max1 [2]min2 [3]max2 [4]shift [5]s [6]s2
static constexpr size_t RSM1_OFF = SC_OFF + 64;         // double rs_m1

// sortable-uint encoding of float for atomic min/max
__device__ __forceinline__ unsigned fenc(float f) {
    unsigned u = __float_as_uint(f);
    return (u >> 31) ? ~u : (u | 0x80000000u);
}
__device__ __forceinline__ float fdec(unsigned e) {
    unsigned u = (e >> 31) ? (e & 0x7fffffffu) : ~e;
    return __uint_as_float(u);
}

// async global->LDS, 16B per lane; LDS base wave-uniform (HW adds lane*16),
// global source address is PER-LANE (m173) -> swizzled LDS via pre-swizzled src.
#define GLDS16(g, l) __builtin_amdgcn_global_load_lds( \
    (const __attribute__((address_space(1))) unsigned int*)(g), \
    (__attribute__((address_space(3))) unsigned int*)(l), 16, 0, 0)

// 16B-chunk XOR swizzle within a 64B row: 2-way-only bank aliasing (free, m136).
__device__ __forceinline__ int swz4(int r) { return (r & 3) ^ ((r >> 2) & 3); }

// ============ K0: weight quantization (int8) + per-channel tables + scalar init ============
__global__ __launch_bounds__(256) void k0_prep(const float* __restrict__ W,
                                               const float* __restrict__ bias,
                                               const float* __restrict__ ln_w,
                                               const float* __restrict__ ln_b,
                                               const float* __restrict__ phsf,
                                               char* __restrict__ ws) {
    int o = blockIdx.x, tid = threadIdx.x;
    __shared__ float red[256];
    __shared__ float fc_sh;
    float m = 0.f;
    for (int j = tid; j < HDIM; j += 256) m = fmaxf(m, fabsf(W[(size_t)o * HDIM + j]));
    red[tid] = m;
    __syncthreads();
    for (int s = 128; s; s >>= 1) { if (tid < s) red[tid] = fmaxf(red[tid], red[tid + s]); __syncthreads(); }
    if (tid == 0) {
        float fc = fmaxf(red[0], 1e-8f) / 127.0f;     // _sym_scale(8,...)
        float hsf = *phsf;
        float bs = fc * hsf;
        fc_sh = fc;
        ((float*)(ws + BS_OFF))[o] = bs;
        ((int*)(ws + BINT_OFF))[o] = (int)rintf(bias[o] / bs);   // _sym_quant(bias,32)
        float sf = sqrtf(768.0f) / 1073741824.0f;                // sqrt(H)/2^30
        float lw = ln_w[o], lb = ln_b[o];
        ((int*)(ws + LNBI_OFF))[o] = (int)floorf((lb / lw) / sf);
        ((float*)(ws + SFO_OFF))[o] = sf * lw;
    }
    __syncthreads();
    float fc = fc_sh;
    char* w8 = (char*)(ws + WINT_OFF);
    for (int j = tid; j < HDIM; j += 256) {
        float q = rintf(W[(size_t)o * HDIM + j] / fc);
        q = fminf(fmaxf(q, -127.f), 126.f);           // clip [-n, n-1]
        w8[(size_t)o * HDIM + j] = (char)q;
    }
    if (blockIdx.x == 0 && tid < 8) {
        unsigned* sc = (unsigned*)(ws + SC_OFF);
        unsigned v = 0u;
        if (tid == 0 || tid == 2) v = 0xFFFFFFFFu;    // min slots
        sc[tid] = v;                                   // max slots + shift -> 0
    }
}

// ============ KP: one-shot activation quantization hs -> int8 (BW-bound) ============
__global__ __launch_bounds__(256) void kp_a8(const float* __restrict__ hs,
                                             const float* __restrict__ phsf,
                                             char* __restrict__ ws) {
    int idx = blockIdx.x * 256 + threadIdx.x;     // 16 elems / thread
    float inv = 1.0f / *phsf;
    const float4* in4 = (const float4*)hs + (size_t)idx * 4;
    unsigned ow[4];
    #pragma unroll
    for (int j = 0; j < 4; ++j) {
        float4 v = in4[j];
        int q0 = (int)rintf(v.x * inv), q1 = (int)rintf(v.y * inv);
        int q2 = (int)rintf(v.z * inv), q3 = (int)rintf(v.w * inv);
        ow[j] = (unsigned)(q0 & 255) | ((unsigned)(q1 & 255) << 8) |
                ((unsigned)(q2 & 255) << 16) | ((unsigned)(q3 & 255) << 24);
    }
    ((uint4*)(ws + WX_OFF))[idx] = make_uint4(ow[0], ow[1], ow[2], ow[3]);
}

// ============ K1: int8 MFMA GEMM, GLDS both operands, counted-vmcnt pipeline ============
#define BM 128
#define BN 192
#define BK 64
#define NKT (HDIM / BK)   // 12
__global__ __launch_bounds__(256) void k1_gemm(const float* __restrict__ inp,
                                               char* __restrict__ ws,
                                               int* __restrict__ accOut) {
    __shared__ alignas(16) char As[2][BM * BK];   // 8 KiB each
    __shared__ alignas(16) char Bs[2][BN * BK];   // 12 KiB each
    __shared__ float rmn[4], rmx[4];
    int tid = threadIdx.x, lane = tid & 63, wave = tid >> 6;
    int wrow = lane & 15, g = lane >> 4;          // g = k-group (0..3)
    int bid = blockIdx.x;
    int xcd = bid & 7, slot = bid >> 3;           // 1024 blocks: 8 XCDs x 128 slots
    int mtile = xcd * 32 + (slot >> 2);           // 32 mtiles/XCD; 4 ntiles share an A panel
    int ntile = slot & 3;
    int t0 = mtile * BM, o0 = ntile * BN;
    const char* a8 = (const char*)(ws + WX_OFF);
    const char* w8 = (const char*)(ws + WINT_OFF);

    const char* asrc[2]; const char* bsrc[3];
    int aldso[2], bldso[3];
    #pragma unroll
    for (int i = 0; i < 2; ++i) {
        int c = i * 256 + tid, r = c >> 2, s = c & 3;
        asrc[i] = a8 + (size_t)(t0 + r) * HDIM + (s ^ swz4(r)) * 16;
        aldso[i] = (i * 256 + wave * 64) * 16;     // wave-uniform
    }
    #pragma unroll
    for (int i = 0; i < 3; ++i) {
        int c = i * 256 + tid, r = c >> 2, s = c & 3;
        bsrc[i] = w8 + (size_t)(o0 + r) * HDIM + (s ^ swz4(r)) * 16;
        bldso[i] = (i * 256 + wave * 64) * 16;
    }

    int wm = wave & 1, wn = wave >> 1;            // wave tile: 64(t) x 96(o)
    int aofs[4], bofs[6];
    #pragma unroll
    for (int mi = 0; mi < 4; ++mi) { int r = wm * 64 + mi * 16 + wrow; aofs[mi] = r * BK + ((g ^ swz4(r)) * 16); }
    #pragma unroll
    for (int nf = 0; nf < 6; ++nf) { int r = wn * 96 + nf * 16 + wrow; bofs[nf] = r * BK + ((g ^ swz4(r)) * 16); }

    #pragma unroll
    for (int i = 0; i < 2; ++i) GLDS16(asrc[i], &As[0][aldso[i]]);
    #pragma unroll
    for (int i = 0; i < 3; ++i) GLDS16(bsrc[i], &Bs[0][bldso[i]]);
    #pragma unroll
    for (int i = 0; i < 2; ++i) GLDS16(asrc[i] + BK, &As[1][aldso[i]]);
    #pragma unroll
    for (int i = 0; i < 3; ++i) GLDS16(bsrc[i] + BK, &Bs[1][bldso[i]]);
    asm volatile("s_waitcnt vmcnt(5)" ::: "memory");
    __builtin_amdgcn_s_barrier();

    v4i acc[4][6] = {};
    for (int kt = 0; kt < NKT; ++kt) {
        int cur = kt & 1;
        u64x2 af[4], bf[6];
        #pragma unroll
        for (int mi = 0; mi < 4; ++mi) af[mi] = *(const u64x2*)&As[cur][aofs[mi]];
        #pragma unroll
        for (int nf = 0; nf < 6; ++nf) bf[nf] = *(const u64x2*)&Bs[cur][bofs[nf]];
        asm volatile("s_waitcnt lgkmcnt(0)" ::: "memory");
        __builtin_amdgcn_s_barrier();             // all waves' reads of buf[cur] retired (WAR guard)
        if (kt + 2 < NKT) {                       // prefetch distance 2 into the buffer just freed
            #pragma unroll
            for (int i = 0; i < 2; ++i) GLDS16(asrc[i] + (kt + 2) * BK, &As[cur][aldso[i]]);
            #pragma unroll
            for (int i = 0; i < 3; ++i) GLDS16(bsrc[i] + (kt + 2) * BK, &Bs[cur][bldso[i]]);
        }
        __builtin_amdgcn_s_setprio(1);
        #pragma unroll
        for (int mi = 0; mi < 4; ++mi)
            #pragma unroll
            for (int nf = 0; nf < 6; ++nf) {
                acc[mi][nf] = __builtin_amdgcn_mfma_i32_16x16x32_i8((long)af[mi][0], (long)bf[nf][0], acc[mi][nf], 0, 0, 0);
                acc[mi][nf] = __builtin_amdgcn_mfma_i32_16x16x32_i8((long)af[mi][1], (long)bf[nf][1], acc[mi][nf], 0, 0, 0);
            }
        __builtin_amdgcn_s_setprio(0);
        if (kt + 2 < NKT) {
            asm volatile("s_waitcnt vmcnt(5)" ::: "memory");   // kt+1's loads done; kt+2's stay in flight
            __builtin_amdgcn_s_barrier();
        } else if (kt + 2 == NKT) {
            asm volatile("s_waitcnt vmcnt(0)" ::: "memory");   // tail: drain last tile
            __builtin_amdgcn_s_barrier();
        }
    }

    // epilogue: bias add, store acc (int32), x_act min/max from coalesced inp reads
    const float* bscale = (const float*)(ws + BS_OFF);
    const int* bint = (const int*)(ws + BINT_OFF);
    int oo[6]; float bsc[6]; int bi[6];
    #pragma unroll
    for (int nf = 0; nf < 6; ++nf) {
        oo[nf] = o0 + wn * 96 + nf * 16 + wrow;
        bsc[nf] = bscale[oo[nf]];
        bi[nf]  = bint[oo[nf]];
    }
    float lmn = 3.402823466e38f, lmx = -3.402823466e38f;
    #pragma unroll
    for (int mi = 0; mi < 4; ++mi)
        #pragma unroll
        for (int r = 0; r < 4; ++r) {
            int t = t0 + wm * 64 + mi * 16 + g * 4 + r;
            size_t rb = (size_t)t * HDIM;
            #pragma unroll
            for (int nf = 0; nf < 6; ++nf) {
                int a = acc[mi][nf][r] + bi[nf];
                size_t idx = rb + oo[nf];
                accOut[idx] = a;
                float xa = (float)a * bsc[nf] + inp[idx];
                lmn = fminf(lmn, xa);
                lmx = fmaxf(lmx, xa);
            }
        }
    #pragma unroll
    for (int off = 32; off; off >>= 1) {
        lmn = fminf(lmn, __shfl_down(lmn, off));
        lmx = fmaxf(lmx, __shfl_down(lmx, off));
    }
    if (lane == 0) { rmn[wave] = lmn; rmx[wave] = lmx; }
    __syncthreads();
    if (tid == 0) {
        float mn = fminf(fminf(rmn[0], rmn[1]), fminf(rmn[2], rmn[3]));
        float mx = fmaxf(fmaxf(rmx[0], rmx[1]), fmaxf(rmx[2], rmx[3]));
        volatile unsigned* sc = (volatile unsigned*)(ws + SC_OFF);
        unsigned emn = fenc(mn), emx = fenc(mx);
        if (emn < sc[0]) atomicMin((unsigned*)&sc[0], emn);   // guarded, monotone
        if (emx > sc[1]) atomicMax((unsigned*)&sc[1], emx);
    }
}

// ============ K2: finalize ln_in_scale s + frexp tables ============
__global__ __launch_bounds__(256) void k2_scale1(const float* __restrict__ pisf, char* __restrict__ ws) {
    __shared__ float s_sh;
    unsigned* sc = (unsigned*)(ws + SC_OFF);
    if (threadIdx.x == 0) {
        float mn = fdec(sc[0]), mx = fdec(sc[1]);
        float s = fmaxf(fmaxf(fabsf(mn), fabsf(mx)), 1e-8f) / 2097151.0f;  // n = 2^21-1
        ((float*)sc)[5] = s;
        s_sh = s;
        double r = (double)(*pisf) / (double)s;
        int ex; double mant = frexp(r, &ex);
        double m1 = floor(mant * 2147483648.0 + 0.5);
        ((double*)(ws + RSM1_OFF))[0] = m1 * exp2((double)(ex - 31));  // m1 * 2^-(31-ex)
    }
    __syncthreads();
    float s = s_sh;
    const float* bs = (const float*)(ws + BS_OFF);
    double* rs1 = (double*)(ws + RS1_OFF);
    for (int o = threadIdx.x; o < HDIM; o += 256) {
        double r = (double)bs[o] / (double)s;
        int ex; double mant = frexp(r, &ex);
        double m = floor(mant * 2147483648.0 + 0.5);
        rs1[o] = m * exp2((double)(ex - 31));
    }
}

// ============ K3: one row per wave, fixed-point requant (22-bit) ============
// Grid NTOK/4: max TLP instead of serial 4-row pipeline; per-wave dependency
// chain (bpermute reduce + f64 log2) overlaps across 8 waves/SIMD.
__global__ __launch_bounds__(256) void k3_rows(char* __restrict__ ws, int* __restrict__ buf,
                                               const float* __restrict__ inp,
                                               const float* __restrict__ pisf) {
    int tid = threadIdx.x, lane = tid & 63, wave = tid >> 6;
    int row = blockIdx.x * 4 + wave;
    const double* rs1 = (const double*)(ws + RS1_OFF);
    double rsm1 = *(const double*)(ws + RSM1_OFF);
    float inv_isf = 1.0f / *pisf;
    size_t base = (size_t)row * HDIM;
    int4 a[3]; float4 x[3];
    #pragma unroll
    for (int c = 0; c < 3; ++c) {
        a[c] = ((const int4*)(buf + base))[lane + 64 * c];
        x[c] = ((const float4*)(inp + base))[lane + 64 * c];
    }
    int q[12];
    int sum = 0;
    #pragma unroll
    for (int c = 0; c < 3; ++c) {
        int o0 = (lane + 64 * c) * 4;
        int av[4] = {a[c].x, a[c].y, a[c].z, a[c].w};
        float xv[4] = {x[c].x, x[c].y, x[c].z, x[c].w};
        #pragma unroll
        for (int j = 0; j < 4; ++j) {
            double q1 = rint((double)av[j] * rs1[o0 + j]);
            int wxj = (int)rintf(xv[j] * inv_isf);
            double qq = q1 + rint((double)wxj * rsm1);
            qq = fmin(fmax(qq, -2097152.0), 2097151.0);   // clip [-2^21, 2^21-1]
            q[c * 4 + j] = (int)qq;
            sum += q[c * 4 + j];
        }
    }
    #pragma unroll
    for (int off = 32; off; off >>= 1) sum += __shfl_xor(sum, off);
    int mean = (int)rint((double)sum / 768.0);
    long long var0 = 0;
    #pragma unroll
    for (int k = 0; k < 12; ++k) { q[k] -= mean; var0 += (long long)q[k] * (long long)q[k]; }
    #pragma unroll
    for (int off = 32; off; off >>= 1) var0 += __shfl_xor(var0, off);
    #pragma unroll
    for (int c = 0; c < 3; ++c) {
        int4 y = {q[c * 4 + 0], q[c * 4 + 1], q[c * 4 + 2], q[c * 4 + 3]};
        ((int4*)(buf + base))[lane + 64 * c] = y;
    }
    if (lane == 0) {
        double v = (double)(var0 < 1 ? 1LL : var0);
        int sr = (int)ceil(0.5 * log2(v) - 16.0);     // ceil(log2(sqrt(v/2^32)))
        if (sr > 0) {
            int* sp = (int*)(ws + SC_OFF) + 4;
            if (sr > *(volatile int*)sp) atomicMax(sp, sr);  // guarded, monotone
        }
    }
}

// ============ K4: one row per wave, IntLayerNorm stats (READ-ONLY) ============
// No longer writes y2 (was 100 MB): stores only the per-row factor (4 B/row);
// k6 recomputes v2 = ((y*factor)>>1)+lnbi bit-exactly from buf + factor.
__global__ __launch_bounds__(256) void k4_rows(char* __restrict__ ws, const int* __restrict__ buf) {
    int tid = threadIdx.x, lane = tid & 63, wave = tid >> 6;
    int row = blockIdx.x * 4 + wave;
    int shift = *(((const int*)(ws + SC_OFF)) + 4);
    const int* lnbi = (const int*)(ws + LNBI_OFF);
    const float* sfo = (const float*)(ws + SFO_OFF);
    __shared__ float rmn[4], rmx[4];
    size_t base = (size_t)row * HDIM;
    int4 y4[3];
    #pragma unroll
    for (int c = 0; c < 3; ++c) y4[c] = ((const int4*)(buf + base))[lane + 64 * c];
    int yv[12];
    #pragma unroll
    for (int c = 0; c < 3; ++c) {
        yv[c * 4 + 0] = y4[c].x; yv[c * 4 + 1] = y4[c].y; yv[c * 4 + 2] = y4[c].z; yv[c * 4 + 3] = y4[c].w;
    }
    long long var = 0;
    #pragma unroll
    for (int k = 0; k < 12; ++k) { int ysh = yv[k] >> shift; var += (long long)ysh * (long long)ysh; }
    #pragma unroll
    for (int off = 32; off; off >>= 1) var += __shfl_xor(var, off);
    double std_int = floor(sqrt((double)var)) * (double)(1LL << shift);
    if (std_int < 1.0) std_int = 1.0;                 // degenerate-row guard
    long long factor = (long long)floor(2147483648.0 / std_int);
    if (lane == 0) ((unsigned*)(ws + FACT_OFF))[row] = (unsigned)factor;
    float lmn = 3.402823466e38f, lmx = -3.402823466e38f;
    #pragma unroll
    for (int c = 0; c < 3; ++c) {
        int o0 = (lane + 64 * c) * 4;
        #pragma unroll
        for (int j = 0; j < 4; ++j) {
            long long t = ((long long)yv[c * 4 + j] * factor) >> 1;   // floor(y*factor/2)
            int v2 = (int)t + lnbi[o0 + j];
            float h = (float)v2 * sfo[o0 + j];
            lmn = fminf(lmn, h);
            lmx = fmaxf(lmx, h);
        }
    }
    #pragma unroll
    for (int off = 32; off; off >>= 1) {
        lmn = fminf(lmn, __shfl_xor(lmn, off));
        lmx = fmaxf(lmx, __shfl_xor(lmx, off));
    }
    if (lane == 0) { rmn[wave] = lmn; rmx[wave] = lmx; }
    __syncthreads();
    if (tid == 0) {
        float mn = fminf(fminf(rmn[0], rmn[1]), fminf(rmn[2], rmn[3]));
        float mx = fmaxf(fmaxf(rmx[0], rmx[1]), fmaxf(rmx[2], rmx[3]));
        volatile unsigned* sc = (volatile unsigned*)(ws + SC_OFF);
        unsigned emn = fenc(mn), emx = fenc(mx);
        if (emn < sc[2]) atomicMin((unsigned*)&sc[2], emn);   // guarded, monotone
        if (emx > sc[3]) atomicMax((unsigned*)&sc[3], emx);
    }
}

// ============ K5: finalize s2 + frexp tables ============
__global__ __launch_bounds__(256) void k5_scale2(char* __restrict__ ws) {
    __shared__ float s_sh;
    unsigned* sc = (unsigned*)(ws + SC_OFF);
    if (threadIdx.x == 0) {
        float mn = fdec(sc[2]), mx = fdec(sc[3]);
        float s2 = fmaxf(fmaxf(fabsf(mn), fabsf(mx)), 1e-8f) / 127.0f;
        ((float*)sc)[6] = s2;
        s_sh = s2;
    }
    __syncthreads();
    float s2 = s_sh;
    const float* sfo = (const float*)(ws + SFO_OFF);
    double* rs2 = (double*)(ws + RS2_OFF);
    for (int o = threadIdx.x; o < HDIM; o += 256) {
        double r = (double)sfo[o] / (double)s2;
        int ex; double mant = frexp(r, &ex);
        double m = floor(mant * 2147483648.0 + 0.5);
        rs2[o] = m * exp2((double)(ex - 31));
    }
}

// ============ K6: LN normalize (recomputed) + 8-bit requant + output write ============
__global__ __launch_bounds__(256) void k6_out(char* __restrict__ ws, float* __restrict__ out) {
    int idx4 = blockIdx.x * 256 + threadIdx.x;
    int4 y = ((const int4*)out)[idx4];               // y_int from k3 (pre-normalize)
    const double* rs2 = (const double*)(ws + RS2_OFF);
    const int* lnbi = (const int*)(ws + LNBI_OFF);
    float s2 = ((const float*)(ws + SC_OFF))[6];
    long long factor = (long long)((const unsigned*)(ws + FACT_OFF))[idx4 / 192];  // row = idx4*4/768
    int base = idx4 * 4;
    int o0 = base % HDIM;
    int yv[4] = {y.x, y.y, y.z, y.w};
    float4 r;
    float* rp = &r.x;
    #pragma unroll
    for (int j = 0; j < 4; ++j) {
        long long t = ((long long)yv[j] * factor) >> 1;   // floor(y*factor/2), identical to k4
        int v2 = (int)t + lnbi[o0 + j];
        double q = rint((double)v2 * rs2[o0 + j]);
        q = fmin(fmax(q, -128.0), 127.0);
        rp[j] = (float)q * s2;
    }
    ((float4*)out)[idx4] = r;
    if (idx4 == 0) out[(size_t)NTOK * HDIM] = s2;
}

extern "C" void kernel_launch(void* const* d_in, const int* in_sizes, int n_in,
                              void* d_out, int out_size, void* d_ws, size_t ws_size,
                              hipStream_t stream) {
    const float* hs   = (const float*)d_in[0];
    const float* phsf = (const float*)d_in[1];
    const float* inp  = (const float*)d_in[2];
    const float* pisf = (const float*)d_in[3];
    const float* W    = (const float*)d_in[4];
    const float* bias = (const float*)d_in[5];
    const float* ln_w = (const float*)d_in[6];
    const float* ln_b = (const float*)d_in[7];
    char* ws = (char*)d_ws;
    float* out = (float*)d_out;
    int* buf = (int*)d_out;   // d_out doubles as the 100MB int32 intermediate buffer

    k0_prep<<<HDIM, 256, 0, stream>>>(W, bias, ln_w, ln_b, phsf, ws);
    kp_a8<<<NTOK * HDIM / 4096, 256, 0, stream>>>(hs, phsf, ws);
    k1_gemm<<<(NTOK / BM) * (HDIM / BN), 256, 0, stream>>>(inp, ws, buf);
    k2_scale1<<<1, 256, 0, stream>>>(pisf, ws);
    k3_rows<<<NTOK / 4, 256, 0, stream>>>(ws, buf, inp, pisf);
    k4_rows<<<NTOK / 4, 256, 0, stream>>>(ws, buf);
    k5_scale2<<<1, 256, 0, stream>>>(ws);
    k6_out<<<NTOK * HDIM / 1024, 256, 0, stream>>>(ws, out);
}

// Round 3
// 412.673 us; speedup vs baseline: 1.1370x; 1.1370x over previous
//
#include <hip/hip_runtime.h>

typedef int   v4i   __attribute__((ext_vector_type(4)));
typedef unsigned long u64x2 __attribute__((ext_vector_type(2)));

#define HDIM 768
#define NTOK 32768

// ---- workspace layout (bytes) ----
static constexpr size_t WX_OFF   = 0;                   // int8 A8 [NTOK*HDIM]
static constexpr size_t WINT_OFF = 25165824;            // int8 W8 [HDIM*HDIM] = 589824 B used (slot is 1179648)
static constexpr size_t FACT_OFF = WINT_OFF + 589824;   // uint32[NTOK] per-row LN factor (131072 B, fits W slot spare)
static constexpr size_t RS1_OFF  = WINT_OFF + 1179648;  // double[768]
static constexpr size_t RS2_OFF  = RS1_OFF + 6144;      // double[768]
static constexpr size_t BS_OFF   = RS2_OFF + 6144;      // float [768] bias_scale
static constexpr size_t BINT_OFF = BS_OFF + 3072;       // int   [768] b_int
static constexpr size_t LNBI_OFF = BINT_OFF + 3072;     // int   [768] LN bias_int
static constexpr size_t SFO_OFF  = LNBI_OFF + 3072;     // float [768] sf_out
static constexpr size_t SC_OFF   = SFO_OFF + 3072;      // scalars: [0]min1 [1]max1 [2]min2 [3]max2 [4]shift [5]s [6]s2
static constexpr size_t RSM1_OFF = SC_OFF + 64;         // double rs_m1

// sortable-uint encoding of float for atomic min/max
__device__ __forceinline__ unsigned fenc(float f) {
    unsigned u = __float_as_uint(f);
    return (u >> 31) ? ~u : (u | 0x80000000u);
}
__device__ __forceinline__ float fdec(unsigned e) {
    unsigned u = (e >> 31) ? (e & 0x7fffffffu) : ~e;
    return __uint_as_float(u);
}

// async global->LDS, 16B per lane; LDS base wave-uniform (HW adds lane*16),
// global source address is PER-LANE (m173) -> swizzled LDS via pre-swizzled src.
#define GLDS16(g, l) __builtin_amdgcn_global_load_lds( \
    (const __attribute__((address_space(1))) unsigned int*)(g), \
    (__attribute__((address_space(3))) unsigned int*)(l), 16, 0, 0)

// 16B-chunk XOR swizzle within a 64B row: 2-way-only bank aliasing (free, m136).
__device__ __forceinline__ int swz4(int r) { return (r & 3) ^ ((r >> 2) & 3); }

// ============ K0: weight quantization (int8) + per-channel tables + scalar init ============
__global__ __launch_bounds__(256) void k0_prep(const float* __restrict__ W,
                                               const float* __restrict__ bias,
                                               const float* __restrict__ ln_w,
                                               const float* __restrict__ ln_b,
                                               const float* __restrict__ phsf,
                                               char* __restrict__ ws) {
    int o = blockIdx.x, tid = threadIdx.x;
    __shared__ float red[256];
    __shared__ float fc_sh;
    float m = 0.f;
    for (int j = tid; j < HDIM; j += 256) m = fmaxf(m, fabsf(W[(size_t)o * HDIM + j]));
    red[tid] = m;
    __syncthreads();
    for (int s = 128; s; s >>= 1) { if (tid < s) red[tid] = fmaxf(red[tid], red[tid + s]); __syncthreads(); }
    if (tid == 0) {
        float fc = fmaxf(red[0], 1e-8f) / 127.0f;     // _sym_scale(8,...)
        float hsf = *phsf;
        float bs = fc * hsf;
        fc_sh = fc;
        ((float*)(ws + BS_OFF))[o] = bs;
        ((int*)(ws + BINT_OFF))[o] = (int)rintf(bias[o] / bs);   // _sym_quant(bias,32)
        float sf = sqrtf(768.0f) / 1073741824.0f;                // sqrt(H)/2^30
        float lw = ln_w[o], lb = ln_b[o];
        ((int*)(ws + LNBI_OFF))[o] = (int)floorf((lb / lw) / sf);
        ((float*)(ws + SFO_OFF))[o] = sf * lw;
    }
    __syncthreads();
    float fc = fc_sh;
    char* w8 = (char*)(ws + WINT_OFF);
    for (int j = tid; j < HDIM; j += 256) {
        float q = rintf(W[(size_t)o * HDIM + j] / fc);
        q = fminf(fmaxf(q, -127.f), 126.f);           // clip [-n, n-1]
        w8[(size_t)o * HDIM + j] = (char)q;
    }
    if (blockIdx.x == 0 && tid < 8) {
        unsigned* sc = (unsigned*)(ws + SC_OFF);
        unsigned v = 0u;
        if (tid == 0 || tid == 2) v = 0xFFFFFFFFu;    // min slots
        sc[tid] = v;                                   // max slots + shift -> 0
    }
}

// ============ KP: one-shot activation quantization hs -> int8 (BW-bound) ============
__global__ __launch_bounds__(256) void kp_a8(const float* __restrict__ hs,
                                             const float* __restrict__ phsf,
                                             char* __restrict__ ws) {
    int idx = blockIdx.x * 256 + threadIdx.x;     // 16 elems / thread
    float inv = 1.0f / *phsf;
    const float4* in4 = (const float4*)hs + (size_t)idx * 4;
    unsigned ow[4];
    #pragma unroll
    for (int j = 0; j < 4; ++j) {
        float4 v = in4[j];
        int q0 = (int)rintf(v.x * inv), q1 = (int)rintf(v.y * inv);
        int q2 = (int)rintf(v.z * inv), q3 = (int)rintf(v.w * inv);
        ow[j] = (unsigned)(q0 & 255) | ((unsigned)(q1 & 255) << 8) |
                ((unsigned)(q2 & 255) << 16) | ((unsigned)(q3 & 255) << 24);
    }
    ((uint4*)(ws + WX_OFF))[idx] = make_uint4(ow[0], ow[1], ow[2], ow[3]);
}

// ============ K1: int8 MFMA GEMM, GLDS both operands, counted-vmcnt pipeline ============
#define BM 128
#define BN 192
#define BK 64
#define NKT (HDIM / BK)   // 12
__global__ __launch_bounds__(256) void k1_gemm(const float* __restrict__ inp,
                                               char* __restrict__ ws,
                                               int* __restrict__ accOut) {
    __shared__ alignas(16) char As[2][BM * BK];   // 8 KiB each
    __shared__ alignas(16) char Bs[2][BN * BK];   // 12 KiB each
    __shared__ float rmn[4], rmx[4];
    int tid = threadIdx.x, lane = tid & 63, wave = tid >> 6;
    int wrow = lane & 15, g = lane >> 4;          // g = k-group (0..3)
    int bid = blockIdx.x;
    int xcd = bid & 7, slot = bid >> 3;           // 1024 blocks: 8 XCDs x 128 slots
    int mtile = xcd * 32 + (slot >> 2);           // 32 mtiles/XCD; 4 ntiles share an A panel
    int ntile = slot & 3;
    int t0 = mtile * BM, o0 = ntile * BN;
    const char* a8 = (const char*)(ws + WX_OFF);
    const char* w8 = (const char*)(ws + WINT_OFF);

    const char* asrc[2]; const char* bsrc[3];
    int aldso[2], bldso[3];
    #pragma unroll
    for (int i = 0; i < 2; ++i) {
        int c = i * 256 + tid, r = c >> 2, s = c & 3;
        asrc[i] = a8 + (size_t)(t0 + r) * HDIM + (s ^ swz4(r)) * 16;
        aldso[i] = (i * 256 + wave * 64) * 16;     // wave-uniform
    }
    #pragma unroll
    for (int i = 0; i < 3; ++i) {
        int c = i * 256 + tid, r = c >> 2, s = c & 3;
        bsrc[i] = w8 + (size_t)(o0 + r) * HDIM + (s ^ swz4(r)) * 16;
        bldso[i] = (i * 256 + wave * 64) * 16;
    }

    int wm = wave & 1, wn = wave >> 1;            // wave tile: 64(t) x 96(o)
    int aofs[4], bofs[6];
    #pragma unroll
    for (int mi = 0; mi < 4; ++mi) { int r = wm * 64 + mi * 16 + wrow; aofs[mi] = r * BK + ((g ^ swz4(r)) * 16); }
    #pragma unroll
    for (int nf = 0; nf < 6; ++nf) { int r = wn * 96 + nf * 16 + wrow; bofs[nf] = r * BK + ((g ^ swz4(r)) * 16); }

    #pragma unroll
    for (int i = 0; i < 2; ++i) GLDS16(asrc[i], &As[0][aldso[i]]);
    #pragma unroll
    for (int i = 0; i < 3; ++i) GLDS16(bsrc[i], &Bs[0][bldso[i]]);
    #pragma unroll
    for (int i = 0; i < 2; ++i) GLDS16(asrc[i] + BK, &As[1][aldso[i]]);
    #pragma unroll
    for (int i = 0; i < 3; ++i) GLDS16(bsrc[i] + BK, &Bs[1][bldso[i]]);
    asm volatile("s_waitcnt vmcnt(5)" ::: "memory");
    __builtin_amdgcn_s_barrier();

    v4i acc[4][6] = {};
    for (int kt = 0; kt < NKT; ++kt) {
        int cur = kt & 1;
        u64x2 af[4], bf[6];
        #pragma unroll
        for (int mi = 0; mi < 4; ++mi) af[mi] = *(const u64x2*)&As[cur][aofs[mi]];
        #pragma unroll
        for (int nf = 0; nf < 6; ++nf) bf[nf] = *(const u64x2*)&Bs[cur][bofs[nf]];
        asm volatile("s_waitcnt lgkmcnt(0)" ::: "memory");
        __builtin_amdgcn_s_barrier();             // all waves' reads of buf[cur] retired (WAR guard)
        if (kt + 2 < NKT) {                       // prefetch distance 2 into the buffer just freed
            #pragma unroll
            for (int i = 0; i < 2; ++i) GLDS16(asrc[i] + (kt + 2) * BK, &As[cur][aldso[i]]);
            #pragma unroll
            for (int i = 0; i < 3; ++i) GLDS16(bsrc[i] + (kt + 2) * BK, &Bs[cur][bldso[i]]);
        }
        __builtin_amdgcn_s_setprio(1);
        #pragma unroll
        for (int mi = 0; mi < 4; ++mi)
            #pragma unroll
            for (int nf = 0; nf < 6; ++nf) {
                acc[mi][nf] = __builtin_amdgcn_mfma_i32_16x16x32_i8((long)af[mi][0], (long)bf[nf][0], acc[mi][nf], 0, 0, 0);
                acc[mi][nf] = __builtin_amdgcn_mfma_i32_16x16x32_i8((long)af[mi][1], (long)bf[nf][1], acc[mi][nf], 0, 0, 0);
            }
        __builtin_amdgcn_s_setprio(0);
        if (kt + 2 < NKT) {
            asm volatile("s_waitcnt vmcnt(5)" ::: "memory");   // kt+1's loads done; kt+2's stay in flight
            __builtin_amdgcn_s_barrier();
        } else if (kt + 2 == NKT) {
            asm volatile("s_waitcnt vmcnt(0)" ::: "memory");   // tail: drain last tile
            __builtin_amdgcn_s_barrier();
        }
    }

    // epilogue: bias add, store acc (int32), x_act min/max from coalesced inp reads
    const float* bscale = (const float*)(ws + BS_OFF);
    const int* bint = (const int*)(ws + BINT_OFF);
    int oo[6]; float bsc[6]; int bi[6];
    #pragma unroll
    for (int nf = 0; nf < 6; ++nf) {
        oo[nf] = o0 + wn * 96 + nf * 16 + wrow;
        bsc[nf] = bscale[oo[nf]];
        bi[nf]  = bint[oo[nf]];
    }
    float lmn = 3.402823466e38f, lmx = -3.402823466e38f;
    #pragma unroll
    for (int mi = 0; mi < 4; ++mi)
        #pragma unroll
        for (int r = 0; r < 4; ++r) {
            int t = t0 + wm * 64 + mi * 16 + g * 4 + r;
            size_t rb = (size_t)t * HDIM;
            #pragma unroll
            for (int nf = 0; nf < 6; ++nf) {
                int a = acc[mi][nf][r] + bi[nf];
                size_t idx = rb + oo[nf];
                accOut[idx] = a;
                float xa = (float)a * bsc[nf] + inp[idx];
                lmn = fminf(lmn, xa);
                lmx = fmaxf(lmx, xa);
            }
        }
    #pragma unroll
    for (int off = 32; off; off >>= 1) {
        lmn = fminf(lmn, __shfl_down(lmn, off));
        lmx = fmaxf(lmx, __shfl_down(lmx, off));
    }
    if (lane == 0) { rmn[wave] = lmn; rmx[wave] = lmx; }
    __syncthreads();
    if (tid == 0) {
        float mn = fminf(fminf(rmn[0], rmn[1]), fminf(rmn[2], rmn[3]));
        float mx = fmaxf(fmaxf(rmx[0], rmx[1]), fmaxf(rmx[2], rmx[3]));
        volatile unsigned* sc = (volatile unsigned*)(ws + SC_OFF);
        unsigned emn = fenc(mn), emx = fenc(mx);
        if (emn < sc[0]) atomicMin((unsigned*)&sc[0], emn);   // guarded, monotone
        if (emx > sc[1]) atomicMax((unsigned*)&sc[1], emx);
    }
}

// ============ K2: finalize ln_in_scale s + frexp tables ============
__global__ __launch_bounds__(256) void k2_scale1(const float* __restrict__ pisf, char* __restrict__ ws) {
    __shared__ float s_sh;
    unsigned* sc = (unsigned*)(ws + SC_OFF);
    if (threadIdx.x == 0) {
        float mn = fdec(sc[0]), mx = fdec(sc[1]);
        float s = fmaxf(fmaxf(fabsf(mn), fabsf(mx)), 1e-8f) / 2097151.0f;  // n = 2^21-1
        ((float*)sc)[5] = s;
        s_sh = s;
        double r = (double)(*pisf) / (double)s;
        int ex; double mant = frexp(r, &ex);
        double m1 = floor(mant * 2147483648.0 + 0.5);
        ((double*)(ws + RSM1_OFF))[0] = m1 * exp2((double)(ex - 31));  // m1 * 2^-(31-ex)
    }
    __syncthreads();
    float s = s_sh;
    const float* bs = (const float*)(ws + BS_OFF);
    double* rs1 = (double*)(ws + RS1_OFF);
    for (int o = threadIdx.x; o < HDIM; o += 256) {
        double r = (double)bs[o] / (double)s;
        int ex; double mant = frexp(r, &ex);
        double m = floor(mant * 2147483648.0 + 0.5);
        rs1[o] = m * exp2((double)(ex - 31));
    }
}

// ============ K3: 4 rows/wave, tables in regs, next-row prefetch ============
// Proven round-1 pipeline shape + rs1 hoisted once per wave (each lane's 12
// channels are the same for all its rows) -> 9 VMEM/row instead of 15.
__global__ __launch_bounds__(256) void k3_rows(char* __restrict__ ws, int* __restrict__ buf,
                                               const float* __restrict__ inp,
                                               const float* __restrict__ pisf) {
    int tid = threadIdx.x, lane = tid & 63, wave = tid >> 6;
    int wid = blockIdx.x * 4 + wave;
    const double* rs1 = (const double*)(ws + RS1_OFF);
    double rsm1 = *(const double*)(ws + RSM1_OFF);
    float inv_isf = 1.0f / *pisf;
    double t_rs1[12];
    #pragma unroll
    for (int c = 0; c < 3; ++c) {
        int o0 = (lane + 64 * c) * 4;
        #pragma unroll
        for (int j = 0; j < 4; ++j) t_rs1[c * 4 + j] = rs1[o0 + j];
    }
    int localShift = 0;
    int4 aP[3]; float4 xP[3];
    {
        size_t b0 = (size_t)(wid * 4) * HDIM;
        #pragma unroll
        for (int c = 0; c < 3; ++c) {
            aP[c] = ((const int4*)(buf + b0))[lane + 64 * c];
            xP[c] = ((const float4*)(inp + b0))[lane + 64 * c];
        }
    }
    for (int rr = 0; rr < 4; ++rr) {
        int4 aN[3]; float4 xN[3];
        if (rr < 3) {   // issue next row's loads; overlap with this row's math
            size_t nb = (size_t)(wid * 4 + rr + 1) * HDIM;
            #pragma unroll
            for (int c = 0; c < 3; ++c) {
                aN[c] = ((const int4*)(buf + nb))[lane + 64 * c];
                xN[c] = ((const float4*)(inp + nb))[lane + 64 * c];
            }
        }
        size_t base = (size_t)(wid * 4 + rr) * HDIM;
        int q[12];
        int sum = 0;
        #pragma unroll
        for (int c = 0; c < 3; ++c) {
            int av[4] = {aP[c].x, aP[c].y, aP[c].z, aP[c].w};
            float xv[4] = {xP[c].x, xP[c].y, xP[c].z, xP[c].w};
            #pragma unroll
            for (int j = 0; j < 4; ++j) {
                double q1 = rint((double)av[j] * t_rs1[c * 4 + j]);
                int wxj = (int)rintf(xv[j] * inv_isf);
                double qq = q1 + rint((double)wxj * rsm1);
                qq = fmin(fmax(qq, -2097152.0), 2097151.0);   // clip [-2^21, 2^21-1]
                q[c * 4 + j] = (int)qq;
                sum += q[c * 4 + j];
            }
        }
        #pragma unroll
        for (int off = 32; off; off >>= 1) sum += __shfl_xor(sum, off);
        int mean = (int)rint((double)sum / 768.0);
        long long var0 = 0;
        #pragma unroll
        for (int k = 0; k < 12; ++k) { q[k] -= mean; var0 += (long long)q[k] * (long long)q[k]; }
        #pragma unroll
        for (int off = 32; off; off >>= 1) var0 += __shfl_xor(var0, off);
        #pragma unroll
        for (int c = 0; c < 3; ++c) {
            int4 y = {q[c * 4 + 0], q[c * 4 + 1], q[c * 4 + 2], q[c * 4 + 3]};
            ((int4*)(buf + base))[lane + 64 * c] = y;
        }
        if (lane == 0) {
            double v = (double)(var0 < 1 ? 1LL : var0);
            int sr = (int)ceil(0.5 * log2(v) - 16.0);     // ceil(log2(sqrt(v/2^32)))
            localShift = max(localShift, sr);
        }
        #pragma unroll
        for (int c = 0; c < 3; ++c) { aP[c] = aN[c]; xP[c] = xN[c]; }
    }
    if (lane == 0 && localShift > 0) {
        int* sp = (int*)(ws + SC_OFF) + 4;
        if (localShift > *(volatile int*)sp) atomicMax(sp, localShift);  // guarded, monotone
    }
}

// ============ K4: 4 rows/wave, read-only LN stats, tables in regs, prefetch ============
// Stores only the per-row factor (4 B/row); k6 recomputes v2 bit-exactly.
__global__ __launch_bounds__(256) void k4_rows(char* __restrict__ ws, const int* __restrict__ buf) {
    int tid = threadIdx.x, lane = tid & 63, wave = tid >> 6;
    int wid = blockIdx.x * 4 + wave;
    int shift = *(((const int*)(ws + SC_OFF)) + 4);
    const int* lnbi = (const int*)(ws + LNBI_OFF);
    const float* sfo = (const float*)(ws + SFO_OFF);
    __shared__ float rmn[4], rmx[4];
    int t_lnbi[12]; float t_sfo[12];
    #pragma unroll
    for (int c = 0; c < 3; ++c) {
        int o0 = (lane + 64 * c) * 4;
        #pragma unroll
        for (int j = 0; j < 4; ++j) { t_lnbi[c * 4 + j] = lnbi[o0 + j]; t_sfo[c * 4 + j] = sfo[o0 + j]; }
    }
    unsigned* fact = (unsigned*)(ws + FACT_OFF);
    float lmn = 3.402823466e38f, lmx = -3.402823466e38f;
    int4 yP[3];
    {
        size_t b0 = (size_t)(wid * 4) * HDIM;
        #pragma unroll
        for (int c = 0; c < 3; ++c) yP[c] = ((const int4*)(buf + b0))[lane + 64 * c];
    }
    for (int rr = 0; rr < 4; ++rr) {
        int4 yN[3];
        if (rr < 3) {
            size_t nb = (size_t)(wid * 4 + rr + 1) * HDIM;
            #pragma unroll
            for (int c = 0; c < 3; ++c) yN[c] = ((const int4*)(buf + nb))[lane + 64 * c];
        }
        int yv[12];
        #pragma unroll
        for (int c = 0; c < 3; ++c) {
            yv[c * 4 + 0] = yP[c].x; yv[c * 4 + 1] = yP[c].y; yv[c * 4 + 2] = yP[c].z; yv[c * 4 + 3] = yP[c].w;
        }
        long long var = 0;
        #pragma unroll
        for (int k = 0; k < 12; ++k) { int ysh = yv[k] >> shift; var += (long long)ysh * (long long)ysh; }
        #pragma unroll
        for (int off = 32; off; off >>= 1) var += __shfl_xor(var, off);
        double std_int = floor(sqrt((double)var)) * (double)(1LL << shift);
        if (std_int < 1.0) std_int = 1.0;                 // degenerate-row guard
        long long factor = (long long)floor(2147483648.0 / std_int);
        if (lane == 0) fact[wid * 4 + rr] = (unsigned)factor;
        #pragma unroll
        for (int k = 0; k < 12; ++k) {
            long long t = ((long long)yv[k] * factor) >> 1;   // floor(y*factor/2)
            int v2 = (int)t + t_lnbi[k];
            float h = (float)v2 * t_sfo[k];
            lmn = fminf(lmn, h);
            lmx = fmaxf(lmx, h);
        }
        #pragma unroll
        for (int c = 0; c < 3; ++c) yP[c] = yN[c];
    }
    #pragma unroll
    for (int off = 32; off; off >>= 1) {
        lmn = fminf(lmn, __shfl_xor(lmn, off));
        lmx = fmaxf(lmx, __shfl_xor(lmx, off));
    }
    if (lane == 0) { rmn[wave] = lmn; rmx[wave] = lmx; }
    __syncthreads();
    if (tid == 0) {
        float mn = fminf(fminf(rmn[0], rmn[1]), fminf(rmn[2], rmn[3]));
        float mx = fmaxf(fmaxf(rmx[0], rmx[1]), fmaxf(rmx[2], rmx[3]));
        volatile unsigned* sc = (volatile unsigned*)(ws + SC_OFF);
        unsigned emn = fenc(mn), emx = fenc(mx);
        if (emn < sc[2]) atomicMin((unsigned*)&sc[2], emn);   // guarded, monotone
        if (emx > sc[3]) atomicMax((unsigned*)&sc[3], emx);
    }
}

// ============ K5: finalize s2 + frexp tables ============
__global__ __launch_bounds__(256) void k5_scale2(char* __restrict__ ws) {
    __shared__ float s_sh;
    unsigned* sc = (unsigned*)(ws + SC_OFF);
    if (threadIdx.x == 0) {
        float mn = fdec(sc[2]), mx = fdec(sc[3]);
        float s2 = fmaxf(fmaxf(fabsf(mn), fabsf(mx)), 1e-8f) / 127.0f;
        ((float*)sc)[6] = s2;
        s_sh = s2;
    }
    __syncthreads();
    float s2 = s_sh;
    const float* sfo = (const float*)(ws + SFO_OFF);
    double* rs2 = (double*)(ws + RS2_OFF);
    for (int o = threadIdx.x; o < HDIM; o += 256) {
        double r = (double)sfo[o] / (double)s2;
        int ex; double mant = frexp(r, &ex);
        double m = floor(mant * 2147483648.0 + 0.5);
        rs2[o] = m * exp2((double)(ex - 31));
    }
}

// ============ K6: 4 rows/wave, LN normalize (recomputed) + 8-bit requant + output ============
__global__ __launch_bounds__(256) void k6_out(char* __restrict__ ws, float* __restrict__ out) {
    int tid = threadIdx.x, lane = tid & 63, wave = tid >> 6;
    int wid = blockIdx.x * 4 + wave;
    const double* rs2 = (const double*)(ws + RS2_OFF);
    const int* lnbi = (const int*)(ws + LNBI_OFF);
    const unsigned* fact = (const unsigned*)(ws + FACT_OFF);
    float s2 = ((const float*)(ws + SC_OFF))[6];
    double t_rs2[12]; int t_lnbi[12];
    #pragma unroll
    for (int c = 0; c < 3; ++c) {
        int o0 = (lane + 64 * c) * 4;
        #pragma unroll
        for (int j = 0; j < 4; ++j) { t_rs2[c * 4 + j] = rs2[o0 + j]; t_lnbi[c * 4 + j] = lnbi[o0 + j]; }
    }
    int* buf = (int*)out;
    int4 yP[3];
    {
        size_t b0 = (size_t)(wid * 4) * HDIM;
        #pragma unroll
        for (int c = 0; c < 3; ++c) yP[c] = ((const int4*)(buf + b0))[lane + 64 * c];
    }
    for (int rr = 0; rr < 4; ++rr) {
        int4 yN[3];
        if (rr < 3) {
            size_t nb = (size_t)(wid * 4 + rr + 1) * HDIM;
            #pragma unroll
            for (int c = 0; c < 3; ++c) yN[c] = ((const int4*)(buf + nb))[lane + 64 * c];
        }
        size_t base = (size_t)(wid * 4 + rr) * HDIM;
        long long factor = (long long)fact[wid * 4 + rr];   // wave-uniform broadcast load
        int yv[12];
        #pragma unroll
        for (int c = 0; c < 3; ++c) {
            yv[c * 4 + 0] = yP[c].x; yv[c * 4 + 1] = yP[c].y; yv[c * 4 + 2] = yP[c].z; yv[c * 4 + 3] = yP[c].w;
        }
        #pragma unroll
        for (int c = 0; c < 3; ++c) {
            float4 r;
            float* rp = &r.x;
            #pragma unroll
            for (int j = 0; j < 4; ++j) {
                int k = c * 4 + j;
                long long t = ((long long)yv[k] * factor) >> 1;   // floor(y*factor/2), identical to k4
                int v2 = (int)t + t_lnbi[k];
                double q = rint((double)v2 * t_rs2[k]);
                q = fmin(fmax(q, -128.0), 127.0);
                rp[j] = (float)q * s2;
            }
            ((float4*)(out + base))[lane + 64 * c] = r;
        }
        #pragma unroll
        for (int c = 0; c < 3; ++c) yP[c] = yN[c];
    }
    if (wid == 0 && tid == 0) out[(size_t)NTOK * HDIM] = s2;
}

extern "C" void kernel_launch(void* const* d_in, const int* in_sizes, int n_in,
                              void* d_out, int out_size, void* d_ws, size_t ws_size,
                              hipStream_t stream) {
    const float* hs   = (const float*)d_in[0];
    const float* phsf = (const float*)d_in[1];
    const float* inp  = (const float*)d_in[2];
    const float* pisf = (const float*)d_in[3];
    const float* W    = (const float*)d_in[4];
    const float* bias = (const float*)d_in[5];
    const float* ln_w = (const float*)d_in[6];
    const float* ln_b = (const float*)d_in[7];
    char* ws = (char*)d_ws;
    float* out = (float*)d_out;
    int* buf = (int*)d_out;   // d_out doubles as the 100MB int32 intermediate buffer

    k0_prep<<<HDIM, 256, 0, stream>>>(W, bias, ln_w, ln_b, phsf, ws);
    kp_a8<<<NTOK * HDIM / 4096, 256, 0, stream>>>(hs, phsf, ws);
    k1_gemm<<<(NTOK / BM) * (HDIM / BN), 256, 0, stream>>>(inp, ws, buf);
    k2_scale1<<<1, 256, 0, stream>>>(pisf, ws);
    k3_rows<<<NTOK / 16, 256, 0, stream>>>(ws, buf, inp, pisf);
    k4_rows<<<NTOK / 16, 256, 0, stream>>>(ws, buf);
    k5_scale2<<<1, 256, 0, stream>>>(ws);
    k6_out<<<NTOK / 16, 256, 0, stream>>>(ws, out);
}